// Round 3
// baseline (733.620 us; speedup 1.0000x reference)
//
#include <hip/hip_runtime.h>

typedef unsigned long long u64;

#define K_TOP 5000
#define NMS_THR_F 0.4f
#define CONF_THR_F 0.6f
#define W_WORDS 80          // ceil(5000/64)=79, padded to 80
#define ROWS_PAD 5056       // mat rows allocated (>= 5008 prefetch reach)
#define CHUNK 8192          // elements per block in select pass
#define TPB 256

// ---------------- pass 1: per-block count of score>thr ----------------
__global__ __launch_bounds__(TPB)
void count_kernel(const float* __restrict__ conf, int N, int* __restrict__ counts) {
  int tid = threadIdx.x;
  long long base = (long long)blockIdx.x * CHUNK + (long long)tid * 32;
  int cnt = 0;
  if (base + 32 <= N) {
    const float4* c4 = (const float4*)conf;
    long long f0 = base >> 1;            // float4 index (2 anchors per float4)
    #pragma unroll
    for (int k = 0; k < 16; ++k) {
      float4 v = c4[f0 + k];
      cnt += (v.y > CONF_THR_F);
      cnt += (v.w > CONF_THR_F);
    }
  } else {
    for (int k = 0; k < 32; ++k) {
      long long n = base + k;
      if (n < N) cnt += (conf[2*n+1] > CONF_THR_F);
    }
  }
  __shared__ int s[TPB];
  s[tid] = cnt; __syncthreads();
  for (int d = TPB/2; d > 0; d >>= 1) {
    if (tid < d) s[tid] += s[tid+d];
    __syncthreads();
  }
  if (tid == 0) counts[blockIdx.x] = s[0];
}

// ---------------- pass 2: exclusive scan of block counts ----------------
__global__ __launch_bounds__(TPB)
void scan_kernel(const int* __restrict__ counts, int* __restrict__ offsets,
                 int* __restrict__ meta, int NB) {
  __shared__ int s[TPB];
  __shared__ int carry;
  int tid = threadIdx.x;
  if (tid == 0) carry = 0;
  __syncthreads();
  for (int base = 0; base < NB; base += TPB) {
    int idx = base + tid;
    int c = (idx < NB) ? counts[idx] : 0;
    s[tid] = c; __syncthreads();
    for (int d = 1; d < TPB; d <<= 1) {
      int v = (tid >= d) ? s[tid - d] : 0;
      __syncthreads();
      s[tid] += v;
      __syncthreads();
    }
    int excl = s[tid] - c + carry;
    if (idx < NB) offsets[idx] = excl;
    __syncthreads();                       // all threads done reading carry
    if (tid == 0) carry += s[TPB-1];
    __syncthreads();
  }
  if (tid == 0) {
    int total = carry;
    meta[0] = total < K_TOP ? total : K_TOP;  // M = number of valid slots
    meta[1] = total;
  }
}

// ---------------- pass 3: stable compaction of first K indices ----------------
__global__ __launch_bounds__(TPB)
void emit_kernel(const float* __restrict__ conf, int N,
                 const int* __restrict__ offsets, int* __restrict__ sel) {
  int tid = threadIdx.x;
  int boff = offsets[blockIdx.x];          // uniform
  if (boff >= K_TOP) return;               // uniform exit, before any barrier
  long long base = (long long)blockIdx.x * CHUNK + (long long)tid * 32;
  unsigned mbits = 0;
  if (base + 32 <= N) {
    const float4* c4 = (const float4*)conf;
    long long f0 = base >> 1;
    #pragma unroll
    for (int k = 0; k < 16; ++k) {
      float4 v = c4[f0 + k];
      mbits |= (unsigned)(v.y > CONF_THR_F) << (2*k);
      mbits |= (unsigned)(v.w > CONF_THR_F) << (2*k+1);
    }
  } else {
    for (int k = 0; k < 32; ++k) {
      long long n = base + k;
      if (n < N && conf[2*n+1] > CONF_THR_F) mbits |= 1u << k;
    }
  }
  int cnt = __popc(mbits);
  __shared__ int s[TPB];
  s[tid] = cnt; __syncthreads();
  for (int d = 1; d < TPB; d <<= 1) {
    int v = (tid >= d) ? s[tid - d] : 0;
    __syncthreads();
    s[tid] += v;
    __syncthreads();
  }
  int rank = boff + s[tid] - cnt;          // exclusive prefix within block + block offset
  if (mbits && rank < K_TOP) {
    for (int k = 0; k < 32; ++k) {
      if ((mbits >> k) & 1u) {
        if (rank < K_TOP) sel[rank] = (int)(base + k);
        ++rank;
      }
    }
  }
}

// scalar inputs arrive as 1-element arrays; dtype could be int32 or float32.
// Decode both ways and pick the interpretation in a sane range (exact for 1664
// either way; 1664.0f's bit pattern reads as 1.15e9 which is rejected).
__device__ __forceinline__ float scalar_to_float(const int* p) {
  int iv = *p;
  float fv = __int_as_float(iv);
  return (iv > 0 && iv < (1 << 20)) ? (float)iv : fv;
}

// ---------------- pass 4: decode boxes/landms/conf for the <=5000 survivors ----
__global__ __launch_bounds__(TPB)
void decode_kernel(const float* __restrict__ loc, const float* __restrict__ conf,
                   const float* __restrict__ landms, const float* __restrict__ priors,
                   const int* __restrict__ psx, const int* __restrict__ psy,
                   const int* __restrict__ sel, const int* __restrict__ meta, int P,
                   float4* __restrict__ boxes, float2* __restrict__ cs,
                   float* __restrict__ pts) {
  int rank = blockIdx.x * TPB + threadIdx.x;
  if (rank >= K_TOP) return;
  int M = meta[0];
  if (rank >= M) {
    boxes[rank] = make_float4(0.f, 0.f, 0.f, 0.f);
    cs[rank] = make_float2(0.f, 0.f);
    #pragma unroll
    for (int k = 0; k < 10; ++k) pts[rank*10 + k] = 0.f;
    return;
  }
  int n = sel[rank];
  int pi = n % P;
  float sx = scalar_to_float(psx), sy = scalar_to_float(psy);
  float4 pr = ((const float4*)priors)[pi];
  float4 lo = ((const float4*)loc)[n];
  // ctr = p[:2] + (loc[:2]*VAR0)*p[2:]
  float cx = __fadd_rn(pr.x, __fmul_rn(__fmul_rn(lo.x, 0.1f), pr.z));
  float cy = __fadd_rn(pr.y, __fmul_rn(__fmul_rn(lo.y, 0.1f), pr.w));
  // wh = p[2:] * exp(loc[2:]*VAR1)
  float w  = __fmul_rn(pr.z, expf(__fmul_rn(lo.z, 0.2f)));
  float h  = __fmul_rn(pr.w, expf(__fmul_rn(lo.w, 0.2f)));
  float hw = __fmul_rn(w, 0.5f), hh = __fmul_rn(h, 0.5f);
  float4 b;
  b.x = __fmul_rn(__fsub_rn(cx, hw), sx);
  b.y = __fmul_rn(__fsub_rn(cy, hh), sy);
  b.z = __fmul_rn(__fadd_rn(cx, hw), sx);
  b.w = __fmul_rn(__fadd_rn(cy, hh), sy);
  boxes[rank] = b;
  cs[rank] = ((const float2*)conf)[n];
  const float2* l2 = (const float2*)landms;
  #pragma unroll
  for (int k = 0; k < 5; ++k) {
    float2 lm = l2[(long long)n*5 + k];
    // pts = (p[:2] + ((p[2:]*l)*VAR0)) * scale
    float px = __fmul_rn(__fadd_rn(pr.x, __fmul_rn(__fmul_rn(pr.z, lm.x), 0.1f)), sx);
    float py = __fmul_rn(__fadd_rn(pr.y, __fmul_rn(__fmul_rn(pr.w, lm.y), 0.1f)), sy);
    pts[rank*10 + 2*k]     = px;
    pts[rank*10 + 2*k + 1] = py;
  }
}

// ---------------- pass 5: suppression bit-matrix ----------------
__device__ __forceinline__ float box_area(float4 a) {
  return __fmul_rn(fmaxf(__fsub_rn(a.z, a.x), 0.f), fmaxf(__fsub_rn(a.w, a.y), 0.f));
}

__global__ __launch_bounds__(64)
void iou_kernel(const float4* __restrict__ boxes, u64* __restrict__ mat) {
  int cb = blockIdx.x;            // col word 0..79
  int rb = blockIdx.y;            // row block 0..78
  int t  = threadIdx.x;
  __shared__ float4 cbox[64];
  __shared__ float  carea[64];
  int j0 = cb * 64;
  int jj = j0 + t;
  float4 bj = (jj < K_TOP) ? boxes[jj] : make_float4(0.f, 0.f, 0.f, 0.f);
  cbox[t]  = bj;
  carea[t] = box_area(bj);
  __syncthreads();
  int i = rb * 64 + t;
  if (i >= K_TOP) return;
  size_t widx = (size_t)i * W_WORDS + cb;
  if (j0 + 63 <= i) { mat[widx] = 0ull; return; }   // whole word is j<=i
  float4 bi = boxes[i];
  float ai = box_area(bi);
  u64 bits = 0;
  #pragma unroll 8
  for (int q = 0; q < 64; ++q) {
    float4 b = cbox[q];
    float iw = fmaxf(__fsub_rn(fminf(bi.z, b.z), fmaxf(bi.x, b.x)), 0.f);
    float ih = fmaxf(__fsub_rn(fminf(bi.w, b.w), fmaxf(bi.y, b.y)), 0.f);
    float inter = __fmul_rn(iw, ih);
    float uni = __fsub_rn(__fadd_rn(ai, carea[q]), inter);
    float iou = __fdiv_rn(inter, fmaxf(uni, 1e-12f));
    int j = j0 + q;
    bits |= (u64)((iou > NMS_THR_F) & (j > i)) << q;
  }
  mat[widx] = bits;
}

// ---------------- pass 6: serial greedy reduce (1 wave, scalar resolve) -------
__device__ __forceinline__ u64 readlane_u64(u64 v, int lane) {
  unsigned lo = (unsigned)__builtin_amdgcn_readlane((int)(unsigned)(v & 0xffffffffull), lane);
  unsigned hi = (unsigned)__builtin_amdgcn_readlane((int)(unsigned)(v >> 32), lane);
  return ((u64)hi << 32) | lo;
}

__global__ __launch_bounds__(64)
void nms_reduce_kernel(const u64* __restrict__ mat, const int* __restrict__ meta,
                       u64* __restrict__ keepw) {
  int t = threadIdx.x;
  int M = meta[0];
  auto initw = [&](int w) -> u64 {
    int start = w * 64;
    if (M <= start) return ~0ull;            // fully invalid -> removed
    if (M >= start + 64) return 0ull;        // fully valid
    return (~0ull) << (M - start);           // bits >= M removed
  };
  u64 r0 = initw(t);                         // word t
  bool has2 = t < (W_WORDS - 64);            // t < 16 owns word 64+t
  u64 r1 = has2 ? initw(64 + t) : ~0ull;
  const int TR = 16;                         // rows per tile (16 | 64: tile never
  const int NT = (K_TOP + TR - 1) / TR;      //  crosses a word boundary)
  u64 A0[TR], A1[TR], B0[TR], B1[TR];
  #pragma unroll
  for (int r = 0; r < TR; ++r) {             // prologue: tile 0 -> A
    A0[r] = mat[(size_t)r * W_WORDS + t];
    A1[r] = has2 ? mat[(size_t)r * W_WORDS + 64 + t] : 0ull;
  }
  for (int g = 0; g < NT; ++g) {
    bool even = (g & 1) == 0;
    if (g + 1 < NT) {                        // prefetch next tile into spare buffer
      if (even) {
        #pragma unroll
        for (int r = 0; r < TR; ++r) {
          size_t row = (size_t)(g + 1) * TR + r;
          B0[r] = mat[row * W_WORDS + t];
          B1[r] = has2 ? mat[row * W_WORDS + 64 + t] : 0ull;
        }
      } else {
        #pragma unroll
        for (int r = 0; r < TR; ++r) {
          size_t row = (size_t)(g + 1) * TR + r;
          A0[r] = mat[row * W_WORDS + t];
          A1[r] = has2 ? mat[row * W_WORDS + 64 + t] : 0ull;
        }
      }
    }
    // ---- scalar resolve of this tile's 16 keep bits (all in column word wi) ----
    int i0 = g * TR;
    int wi = i0 >> 6;                        // uniform: 0..78
    int sh = i0 & 63;                        // 0,16,32,48
    u64 cur = (wi < 64) ? readlane_u64(r0, wi) : readlane_u64(r1, wi - 64);
    unsigned keep16 = 0;
    #pragma unroll
    for (int r = 0; r < TR; ++r) {
      int i = i0 + r;
      if (i < K_TOP) {
        if (!((cur >> (sh + r)) & 1ull)) {   // row i kept
          keep16 |= 1u << r;
          u64 d = even ? ((wi < 64) ? readlane_u64(A0[r], wi) : readlane_u64(A1[r], wi - 64))
                       : ((wi < 64) ? readlane_u64(B0[r], wi) : readlane_u64(B1[r], wi - 64));
          cur |= d;                          // in-tile forward suppression
        }
      }
    }
    // ---- apply kept rows' full-width masks (uniform branches, no cross-lane) ----
    #pragma unroll
    for (int r = 0; r < TR; ++r) {
      if ((keep16 >> r) & 1u) {
        if (even) { r0 |= A0[r]; r1 |= A1[r]; }
        else      { r0 |= B0[r]; r1 |= B1[r]; }
      }
    }
  }
  keepw[t] = ~r0;
  if (has2) keepw[64 + t] = ~r1;
}

// ---------------- pass 7: final masked write ----------------
__global__ __launch_bounds__(TPB)
void finalize_kernel(const float4* __restrict__ boxes, const float2* __restrict__ cs,
                     const float* __restrict__ pts, const u64* __restrict__ keepw,
                     float* __restrict__ out) {
  int rank = blockIdx.x * TPB + threadIdx.x;
  if (rank >= K_TOP) return;
  float m = ((keepw[rank >> 6] >> (rank & 63)) & 1ull) ? 1.0f : 0.0f;
  const int PTS_OFF  = K_TOP * 2;    // 10000
  const int BOX_OFF  = K_TOP * 12;   // 60000
  const int KEEP_OFF = K_TOP * 16;   // 80000
  float2 c = cs[rank];
  out[rank*2 + 0] = c.x * m;
  out[rank*2 + 1] = c.y * m;
  #pragma unroll
  for (int k = 0; k < 10; ++k) out[PTS_OFF + rank*10 + k] = pts[rank*10 + k] * m;
  float4 b = boxes[rank];
  out[BOX_OFF + rank*4 + 0] = b.x * m;
  out[BOX_OFF + rank*4 + 1] = b.y * m;
  out[BOX_OFF + rank*4 + 2] = b.z * m;
  out[BOX_OFF + rank*4 + 3] = b.w * m;
  out[KEEP_OFF + rank] = m;
}

extern "C" void kernel_launch(void* const* d_in, const int* in_sizes, int n_in,
                              void* d_out, int out_size, void* d_ws, size_t ws_size,
                              hipStream_t stream) {
  const float* loc    = (const float*)d_in[0];
  const float* conf   = (const float*)d_in[1];
  const float* landms = (const float*)d_in[2];
  const float* priors = (const float*)d_in[3];
  const int*   psx    = (const int*)d_in[4];
  const int*   psy    = (const int*)d_in[5];
  int P = in_sizes[3] / 4;
  int N = in_sizes[1] / 2;
  int NB = (N + CHUNK - 1) / CHUNK;

  char* ws = (char*)d_ws;
  size_t off = 0;
  u64*    mat    = (u64*)(ws + off);    off += (size_t)ROWS_PAD * W_WORDS * 8; // 3.24 MB
  u64*    keepw  = (u64*)(ws + off);    off += (size_t)W_WORDS * 8;
  float4* boxes  = (float4*)(ws + off); off += (size_t)K_TOP * 16;
  float2* cs     = (float2*)(ws + off); off += (size_t)K_TOP * 8;
  float*  pts    = (float*)(ws + off);  off += (size_t)K_TOP * 40;
  int*    sel    = (int*)(ws + off);    off += (size_t)K_TOP * 4;
  int*    counts = (int*)(ws + off);    off += (size_t)NB * 4;
  int*    offs   = (int*)(ws + off);    off += (size_t)NB * 4;
  int*    meta   = (int*)(ws + off);    off += 64;

  count_kernel<<<NB, TPB, 0, stream>>>(conf, N, counts);
  scan_kernel<<<1, TPB, 0, stream>>>(counts, offs, meta, NB);
  emit_kernel<<<NB, TPB, 0, stream>>>(conf, N, offs, sel);
  int dgrid = (K_TOP + TPB - 1) / TPB;
  decode_kernel<<<dgrid, TPB, 0, stream>>>(loc, conf, landms, priors, psx, psy,
                                           sel, meta, P, boxes, cs, pts);
  dim3 ig(W_WORDS, (K_TOP + 63) / 64);   // 80 x 79
  iou_kernel<<<ig, 64, 0, stream>>>(boxes, mat);
  nms_reduce_kernel<<<1, 64, 0, stream>>>(mat, meta, keepw);
  finalize_kernel<<<dgrid, TPB, 0, stream>>>(boxes, cs, pts, keepw, (float*)d_out);
}

// Round 4
// 437.998 us; speedup vs baseline: 1.6749x; 1.6749x over previous
//
#include <hip/hip_runtime.h>

typedef unsigned long long u64;

#define K_TOP 5000
#define NMS_THR_F 0.4f
#define CONF_THR_F 0.6f
#define W_WORDS 80          // ceil(5000/64)=79, padded to 80
#define ROWS_PAD 5056       // mat rows allocated (>= 5008 tile reach)
#define CHUNK 8192          // elements per block in select pass
#define TPB 256

// ---------------- pass 1: per-block count of score>thr ----------------
__global__ __launch_bounds__(TPB)
void count_kernel(const float* __restrict__ conf, int N, int* __restrict__ counts) {
  int tid = threadIdx.x;
  long long base = (long long)blockIdx.x * CHUNK + (long long)tid * 32;
  int cnt = 0;
  if (base + 32 <= N) {
    const float4* c4 = (const float4*)conf;
    long long f0 = base >> 1;            // float4 index (2 anchors per float4)
    #pragma unroll
    for (int k = 0; k < 16; ++k) {
      float4 v = c4[f0 + k];
      cnt += (v.y > CONF_THR_F);
      cnt += (v.w > CONF_THR_F);
    }
  } else {
    for (int k = 0; k < 32; ++k) {
      long long n = base + k;
      if (n < N) cnt += (conf[2*n+1] > CONF_THR_F);
    }
  }
  __shared__ int s[TPB];
  s[tid] = cnt; __syncthreads();
  for (int d = TPB/2; d > 0; d >>= 1) {
    if (tid < d) s[tid] += s[tid+d];
    __syncthreads();
  }
  if (tid == 0) counts[blockIdx.x] = s[0];
}

// ---------------- pass 2: exclusive scan of block counts ----------------
__global__ __launch_bounds__(TPB)
void scan_kernel(const int* __restrict__ counts, int* __restrict__ offsets,
                 int* __restrict__ meta, int NB) {
  __shared__ int s[TPB];
  __shared__ int carry;
  int tid = threadIdx.x;
  if (tid == 0) carry = 0;
  __syncthreads();
  for (int base = 0; base < NB; base += TPB) {
    int idx = base + tid;
    int c = (idx < NB) ? counts[idx] : 0;
    s[tid] = c; __syncthreads();
    for (int d = 1; d < TPB; d <<= 1) {
      int v = (tid >= d) ? s[tid - d] : 0;
      __syncthreads();
      s[tid] += v;
      __syncthreads();
    }
    int excl = s[tid] - c + carry;
    if (idx < NB) offsets[idx] = excl;
    __syncthreads();                       // all threads done reading carry
    if (tid == 0) carry += s[TPB-1];
    __syncthreads();
  }
  if (tid == 0) {
    int total = carry;
    meta[0] = total < K_TOP ? total : K_TOP;  // M = number of valid slots
    meta[1] = total;
  }
}

// ---------------- pass 3: stable compaction of first K indices ----------------
__global__ __launch_bounds__(TPB)
void emit_kernel(const float* __restrict__ conf, int N,
                 const int* __restrict__ offsets, int* __restrict__ sel) {
  int tid = threadIdx.x;
  int boff = offsets[blockIdx.x];          // uniform
  if (boff >= K_TOP) return;               // uniform exit, before any barrier
  long long base = (long long)blockIdx.x * CHUNK + (long long)tid * 32;
  unsigned mbits = 0;
  if (base + 32 <= N) {
    const float4* c4 = (const float4*)conf;
    long long f0 = base >> 1;
    #pragma unroll
    for (int k = 0; k < 16; ++k) {
      float4 v = c4[f0 + k];
      mbits |= (unsigned)(v.y > CONF_THR_F) << (2*k);
      mbits |= (unsigned)(v.w > CONF_THR_F) << (2*k+1);
    }
  } else {
    for (int k = 0; k < 32; ++k) {
      long long n = base + k;
      if (n < N && conf[2*n+1] > CONF_THR_F) mbits |= 1u << k;
    }
  }
  int cnt = __popc(mbits);
  __shared__ int s[TPB];
  s[tid] = cnt; __syncthreads();
  for (int d = 1; d < TPB; d <<= 1) {
    int v = (tid >= d) ? s[tid - d] : 0;
    __syncthreads();
    s[tid] += v;
    __syncthreads();
  }
  int rank = boff + s[tid] - cnt;          // exclusive prefix within block + block offset
  if (mbits && rank < K_TOP) {
    for (int k = 0; k < 32; ++k) {
      if ((mbits >> k) & 1u) {
        if (rank < K_TOP) sel[rank] = (int)(base + k);
        ++rank;
      }
    }
  }
}

// scalar inputs arrive as 1-element arrays; dtype could be int32 or float32.
// Decode both ways and pick the interpretation in a sane range (exact for 1664
// either way; 1664.0f's bit pattern reads as 1.15e9 which is rejected).
__device__ __forceinline__ float scalar_to_float(const int* p) {
  int iv = *p;
  float fv = __int_as_float(iv);
  return (iv > 0 && iv < (1 << 20)) ? (float)iv : fv;
}

// ---------------- pass 4: decode boxes/landms/conf for the <=5000 survivors ----
__global__ __launch_bounds__(TPB)
void decode_kernel(const float* __restrict__ loc, const float* __restrict__ conf,
                   const float* __restrict__ landms, const float* __restrict__ priors,
                   const int* __restrict__ psx, const int* __restrict__ psy,
                   const int* __restrict__ sel, const int* __restrict__ meta, int P,
                   float4* __restrict__ boxes, float2* __restrict__ cs,
                   float* __restrict__ pts) {
  int rank = blockIdx.x * TPB + threadIdx.x;
  if (rank >= K_TOP) return;
  int M = meta[0];
  if (rank >= M) {
    boxes[rank] = make_float4(0.f, 0.f, 0.f, 0.f);
    cs[rank] = make_float2(0.f, 0.f);
    #pragma unroll
    for (int k = 0; k < 10; ++k) pts[rank*10 + k] = 0.f;
    return;
  }
  int n = sel[rank];
  int pi = n % P;
  float sx = scalar_to_float(psx), sy = scalar_to_float(psy);
  float4 pr = ((const float4*)priors)[pi];
  float4 lo = ((const float4*)loc)[n];
  // ctr = p[:2] + (loc[:2]*VAR0)*p[2:]
  float cx = __fadd_rn(pr.x, __fmul_rn(__fmul_rn(lo.x, 0.1f), pr.z));
  float cy = __fadd_rn(pr.y, __fmul_rn(__fmul_rn(lo.y, 0.1f), pr.w));
  // wh = p[2:] * exp(loc[2:]*VAR1)
  float w  = __fmul_rn(pr.z, expf(__fmul_rn(lo.z, 0.2f)));
  float h  = __fmul_rn(pr.w, expf(__fmul_rn(lo.w, 0.2f)));
  float hw = __fmul_rn(w, 0.5f), hh = __fmul_rn(h, 0.5f);
  float4 b;
  b.x = __fmul_rn(__fsub_rn(cx, hw), sx);
  b.y = __fmul_rn(__fsub_rn(cy, hh), sy);
  b.z = __fmul_rn(__fadd_rn(cx, hw), sx);
  b.w = __fmul_rn(__fadd_rn(cy, hh), sy);
  boxes[rank] = b;
  cs[rank] = ((const float2*)conf)[n];
  const float2* l2 = (const float2*)landms;
  #pragma unroll
  for (int k = 0; k < 5; ++k) {
    float2 lm = l2[(long long)n*5 + k];
    // pts = (p[:2] + ((p[2:]*l)*VAR0)) * scale
    float px = __fmul_rn(__fadd_rn(pr.x, __fmul_rn(__fmul_rn(pr.z, lm.x), 0.1f)), sx);
    float py = __fmul_rn(__fadd_rn(pr.y, __fmul_rn(__fmul_rn(pr.w, lm.y), 0.1f)), sy);
    pts[rank*10 + 2*k]     = px;
    pts[rank*10 + 2*k + 1] = py;
  }
}

// ---------------- pass 5: suppression bit-matrix ----------------
__device__ __forceinline__ float box_area(float4 a) {
  return __fmul_rn(fmaxf(__fsub_rn(a.z, a.x), 0.f), fmaxf(__fsub_rn(a.w, a.y), 0.f));
}

__global__ __launch_bounds__(64)
void iou_kernel(const float4* __restrict__ boxes, u64* __restrict__ mat) {
  int cb = blockIdx.x;            // col word 0..79
  int rb = blockIdx.y;            // row block 0..78
  int t  = threadIdx.x;
  __shared__ float4 cbox[64];
  __shared__ float  carea[64];
  int j0 = cb * 64;
  int jj = j0 + t;
  float4 bj = (jj < K_TOP) ? boxes[jj] : make_float4(0.f, 0.f, 0.f, 0.f);
  cbox[t]  = bj;
  carea[t] = box_area(bj);
  __syncthreads();
  int i = rb * 64 + t;
  if (i >= K_TOP) return;
  size_t widx = (size_t)i * W_WORDS + cb;
  if (j0 + 63 <= i) { mat[widx] = 0ull; return; }   // whole word is j<=i
  float4 bi = boxes[i];
  float ai = box_area(bi);
  u64 bits = 0;
  #pragma unroll 8
  for (int q = 0; q < 64; ++q) {
    float4 b = cbox[q];
    float iw = fmaxf(__fsub_rn(fminf(bi.z, b.z), fmaxf(bi.x, b.x)), 0.f);
    float ih = fmaxf(__fsub_rn(fminf(bi.w, b.w), fmaxf(bi.y, b.y)), 0.f);
    float inter = __fmul_rn(iw, ih);
    float uni = __fsub_rn(__fadd_rn(ai, carea[q]), inter);
    float iou = __fdiv_rn(inter, fmaxf(uni, 1e-12f));
    int j = j0 + q;
    bits |= (u64)((iou > NMS_THR_F) & (j > i)) << q;
  }
  mat[widx] = bits;
}

// ---------------- pass 6: serial greedy reduce, LDS-pipelined -----------------
// Single wave. Tiles of TR=16 rows stream global->LDS via global_load_lds
// (zero VGPR staging), 4 slots deep, counted vmcnt so 3 tiles stay in flight.
#define TR 16
#define PIPE 4
#define TILE_WORDS (TR * W_WORDS)            // 1280 u64
#define TILE_BYTES (TILE_WORDS * 8)          // 10240 B
#define COPIES_PER_TILE (TILE_BYTES / 1024)  // 10 (64 lanes x 16 B each)

__device__ __forceinline__ u64 readlane_u64(u64 v, int lane) {
  unsigned lo = (unsigned)__builtin_amdgcn_readlane((int)(unsigned)(v & 0xffffffffull), lane);
  unsigned hi = (unsigned)__builtin_amdgcn_readlane((int)(unsigned)(v >> 32), lane);
  return ((u64)hi << 32) | lo;
}

__device__ __forceinline__ void async_copy16(const void* g, void* l) {
  __builtin_amdgcn_global_load_lds((const __attribute__((address_space(1))) void*)g,
                                   (__attribute__((address_space(3))) void*)l,
                                   16, 0, 0);
}

__device__ __forceinline__ void issue_tile(const char* matb, u64* slotp, int tile, int lane) {
  const char* src = matb + (size_t)tile * TILE_BYTES + (size_t)lane * 16;
  char* dst = (char*)slotp;                  // wave-uniform; HW adds lane*16
  #pragma unroll
  for (int c = 0; c < COPIES_PER_TILE; ++c)
    async_copy16(src + c * 1024, dst + c * 1024);
}

__global__ __launch_bounds__(64)
void nms_reduce_kernel(const u64* __restrict__ mat, const int* __restrict__ meta,
                       u64* __restrict__ keepw) {
  __shared__ __align__(16) u64 sbuf[PIPE][TILE_WORDS];   // 40 KB
  int t = threadIdx.x;
  int M = meta[0];
  const char* matb = (const char*)mat;
  const int NT = (K_TOP + TR - 1) / TR;      // 313
  // deep prefetch: tiles 0..2
  issue_tile(matb, sbuf[0], 0, t);
  issue_tile(matb, sbuf[1], 1, t);
  issue_tile(matb, sbuf[2], 2, t);

  auto initw = [&](int w) -> u64 {
    int start = w * 64;
    if (M <= start) return ~0ull;            // fully invalid -> removed
    if (M >= start + 64) return 0ull;        // fully valid
    return (~0ull) << (M - start);           // bits >= M removed
  };
  u64 r0w = initw(t);                        // removed-state word t
  u64 r1w = (t < 16) ? initw(64 + t) : ~0ull; // lanes 0..15 own words 64..79

  for (int g = 0; g < NT; ++g) {
    int rem = NT - 1 - g;
    if (rem >= 3) issue_tile(matb, sbuf[(g + 3) & 3], g + 3, t);
    // counted wait: oldest tile (g) complete, up to 3 newer tiles in flight
    if (rem >= 3)      { asm volatile("s_waitcnt vmcnt(30)" ::: "memory"); }
    else if (rem == 2) { asm volatile("s_waitcnt vmcnt(20)" ::: "memory"); }
    else if (rem == 1) { asm volatile("s_waitcnt vmcnt(10)" ::: "memory"); }
    else               { asm volatile("s_waitcnt vmcnt(0)"  ::: "memory"); }
    __builtin_amdgcn_sched_barrier(0);

    const u64* slot = sbuf[g & 3];
    u64 w0[TR], w1[TR];
    #pragma unroll
    for (int r = 0; r < TR; ++r) {           // batch all ds_reads up front
      w0[r] = slot[r * W_WORDS + t];
      w1[r] = slot[r * W_WORDS + 64 + (t & 15)];
    }
    // ---- scalar resolve of this tile's keep bits (all in column word wi) ----
    int i0 = g * TR;
    int wi = i0 >> 6;                        // uniform 0..78 (16 | 64)
    int sh = i0 & 63;                        // 0,16,32,48
    u64 cur = (wi < 64) ? readlane_u64(r0w, wi) : readlane_u64(r1w, wi - 64);
    unsigned keep16 = 0;
    #pragma unroll
    for (int r = 0; r < TR; ++r) {
      int i = i0 + r;
      if (i < K_TOP && !((cur >> (sh + r)) & 1ull)) {   // row i kept
        keep16 |= 1u << r;
        cur |= (wi < 64) ? readlane_u64(w0[r], wi)      // in-tile forward suppression
                         : readlane_u64(w1[r], wi - 64);
      }
    }
    // ---- branchless apply of kept rows' masks ----
    #pragma unroll
    for (int r = 0; r < TR; ++r) {
      u64 msk = 0ull - (u64)((keep16 >> r) & 1u);
      r0w |= (w0[r] & msk);
      r1w |= (w1[r] & msk);                  // lanes t>=16 compute garbage, never stored
    }
  }
  keepw[t] = ~r0w;
  if (t < 16) keepw[64 + t] = ~r1w;
}

// ---------------- pass 7: final masked write ----------------
__global__ __launch_bounds__(TPB)
void finalize_kernel(const float4* __restrict__ boxes, const float2* __restrict__ cs,
                     const float* __restrict__ pts, const u64* __restrict__ keepw,
                     float* __restrict__ out) {
  int rank = blockIdx.x * TPB + threadIdx.x;
  if (rank >= K_TOP) return;
  float m = ((keepw[rank >> 6] >> (rank & 63)) & 1ull) ? 1.0f : 0.0f;
  const int PTS_OFF  = K_TOP * 2;    // 10000
  const int BOX_OFF  = K_TOP * 12;   // 60000
  const int KEEP_OFF = K_TOP * 16;   // 80000
  float2 c = cs[rank];
  out[rank*2 + 0] = c.x * m;
  out[rank*2 + 1] = c.y * m;
  #pragma unroll
  for (int k = 0; k < 10; ++k) out[PTS_OFF + rank*10 + k] = pts[rank*10 + k] * m;
  float4 b = boxes[rank];
  out[BOX_OFF + rank*4 + 0] = b.x * m;
  out[BOX_OFF + rank*4 + 1] = b.y * m;
  out[BOX_OFF + rank*4 + 2] = b.z * m;
  out[BOX_OFF + rank*4 + 3] = b.w * m;
  out[KEEP_OFF + rank] = m;
}

extern "C" void kernel_launch(void* const* d_in, const int* in_sizes, int n_in,
                              void* d_out, int out_size, void* d_ws, size_t ws_size,
                              hipStream_t stream) {
  const float* loc    = (const float*)d_in[0];
  const float* conf   = (const float*)d_in[1];
  const float* landms = (const float*)d_in[2];
  const float* priors = (const float*)d_in[3];
  const int*   psx    = (const int*)d_in[4];
  const int*   psy    = (const int*)d_in[5];
  int P = in_sizes[3] / 4;
  int N = in_sizes[1] / 2;
  int NB = (N + CHUNK - 1) / CHUNK;

  char* ws = (char*)d_ws;
  size_t off = 0;
  u64*    mat    = (u64*)(ws + off);    off += (size_t)ROWS_PAD * W_WORDS * 8; // 3.24 MB
  u64*    keepw  = (u64*)(ws + off);    off += (size_t)W_WORDS * 8;
  float4* boxes  = (float4*)(ws + off); off += (size_t)K_TOP * 16;
  float2* cs     = (float2*)(ws + off); off += (size_t)K_TOP * 8;
  float*  pts    = (float*)(ws + off);  off += (size_t)K_TOP * 40;
  int*    sel    = (int*)(ws + off);    off += (size_t)K_TOP * 4;
  int*    counts = (int*)(ws + off);    off += (size_t)NB * 4;
  int*    offs   = (int*)(ws + off);    off += (size_t)NB * 4;
  int*    meta   = (int*)(ws + off);    off += 64;

  count_kernel<<<NB, TPB, 0, stream>>>(conf, N, counts);
  scan_kernel<<<1, TPB, 0, stream>>>(counts, offs, meta, NB);
  emit_kernel<<<NB, TPB, 0, stream>>>(conf, N, offs, sel);
  int dgrid = (K_TOP + TPB - 1) / TPB;
  decode_kernel<<<dgrid, TPB, 0, stream>>>(loc, conf, landms, priors, psx, psy,
                                           sel, meta, P, boxes, cs, pts);
  dim3 ig(W_WORDS, (K_TOP + 63) / 64);   // 80 x 79
  iou_kernel<<<ig, 64, 0, stream>>>(boxes, mat);
  nms_reduce_kernel<<<1, 64, 0, stream>>>(mat, meta, keepw);
  finalize_kernel<<<dgrid, TPB, 0, stream>>>(boxes, cs, pts, keepw, (float*)d_out);
}

// Round 5
// 417.493 us; speedup vs baseline: 1.7572x; 1.0491x over previous
//
#include <hip/hip_runtime.h>

typedef unsigned long long u64;

#define K_TOP 5000
#define NMS_THR_F 0.4f
#define CONF_THR_F 0.6f
#define W_WORDS 80          // ceil(5000/64)=79, padded to 80
#define ROWS_PAD 5056       // mat rows allocated (>= 5008 tile reach)
#define CHUNK 8192          // elements per block in select pass
#define TPB 256

// ---------------- pass 1: per-block count of score>thr ----------------
__global__ __launch_bounds__(TPB)
void count_kernel(const float* __restrict__ conf, int N, int* __restrict__ counts) {
  int tid = threadIdx.x;
  long long base = (long long)blockIdx.x * CHUNK + (long long)tid * 32;
  int cnt = 0;
  if (base + 32 <= N) {
    const float4* c4 = (const float4*)conf;
    long long f0 = base >> 1;            // float4 index (2 anchors per float4)
    #pragma unroll
    for (int k = 0; k < 16; ++k) {
      float4 v = c4[f0 + k];
      cnt += (v.y > CONF_THR_F);
      cnt += (v.w > CONF_THR_F);
    }
  } else {
    for (int k = 0; k < 32; ++k) {
      long long n = base + k;
      if (n < N) cnt += (conf[2*n+1] > CONF_THR_F);
    }
  }
  __shared__ int s[TPB];
  s[tid] = cnt; __syncthreads();
  for (int d = TPB/2; d > 0; d >>= 1) {
    if (tid < d) s[tid] += s[tid+d];
    __syncthreads();
  }
  if (tid == 0) counts[blockIdx.x] = s[0];
}

// ---------------- pass 2: exclusive scan of block counts ----------------
__global__ __launch_bounds__(TPB)
void scan_kernel(const int* __restrict__ counts, int* __restrict__ offsets,
                 int* __restrict__ meta, int NB) {
  __shared__ int s[TPB];
  __shared__ int carry;
  int tid = threadIdx.x;
  if (tid == 0) carry = 0;
  __syncthreads();
  for (int base = 0; base < NB; base += TPB) {
    int idx = base + tid;
    int c = (idx < NB) ? counts[idx] : 0;
    s[tid] = c; __syncthreads();
    for (int d = 1; d < TPB; d <<= 1) {
      int v = (tid >= d) ? s[tid - d] : 0;
      __syncthreads();
      s[tid] += v;
      __syncthreads();
    }
    int excl = s[tid] - c + carry;
    if (idx < NB) offsets[idx] = excl;
    __syncthreads();                       // all threads done reading carry
    if (tid == 0) carry += s[TPB-1];
    __syncthreads();
  }
  if (tid == 0) {
    int total = carry;
    meta[0] = total < K_TOP ? total : K_TOP;  // M = number of valid slots
    meta[1] = total;
  }
}

// ---------------- pass 3: stable compaction of first K indices ----------------
__global__ __launch_bounds__(TPB)
void emit_kernel(const float* __restrict__ conf, int N,
                 const int* __restrict__ offsets, int* __restrict__ sel) {
  int tid = threadIdx.x;
  int boff = offsets[blockIdx.x];          // uniform
  if (boff >= K_TOP) return;               // uniform exit, before any barrier
  long long base = (long long)blockIdx.x * CHUNK + (long long)tid * 32;
  unsigned mbits = 0;
  if (base + 32 <= N) {
    const float4* c4 = (const float4*)conf;
    long long f0 = base >> 1;
    #pragma unroll
    for (int k = 0; k < 16; ++k) {
      float4 v = c4[f0 + k];
      mbits |= (unsigned)(v.y > CONF_THR_F) << (2*k);
      mbits |= (unsigned)(v.w > CONF_THR_F) << (2*k+1);
    }
  } else {
    for (int k = 0; k < 32; ++k) {
      long long n = base + k;
      if (n < N && conf[2*n+1] > CONF_THR_F) mbits |= 1u << k;
    }
  }
  int cnt = __popc(mbits);
  __shared__ int s[TPB];
  s[tid] = cnt; __syncthreads();
  for (int d = 1; d < TPB; d <<= 1) {
    int v = (tid >= d) ? s[tid - d] : 0;
    __syncthreads();
    s[tid] += v;
    __syncthreads();
  }
  int rank = boff + s[tid] - cnt;          // exclusive prefix within block + block offset
  if (mbits && rank < K_TOP) {
    for (int k = 0; k < 32; ++k) {
      if ((mbits >> k) & 1u) {
        if (rank < K_TOP) sel[rank] = (int)(base + k);
        ++rank;
      }
    }
  }
}

// scalar inputs arrive as 1-element arrays; dtype could be int32 or float32.
// Decode both ways and pick the interpretation in a sane range (exact for 1664
// either way; 1664.0f's bit pattern reads as 1.15e9 which is rejected).
__device__ __forceinline__ float scalar_to_float(const int* p) {
  int iv = *p;
  float fv = __int_as_float(iv);
  return (iv > 0 && iv < (1 << 20)) ? (float)iv : fv;
}

// ---------------- pass 4: decode boxes/landms/conf for the <=5000 survivors ----
__global__ __launch_bounds__(TPB)
void decode_kernel(const float* __restrict__ loc, const float* __restrict__ conf,
                   const float* __restrict__ landms, const float* __restrict__ priors,
                   const int* __restrict__ psx, const int* __restrict__ psy,
                   const int* __restrict__ sel, const int* __restrict__ meta, int P,
                   float4* __restrict__ boxes, float2* __restrict__ cs,
                   float* __restrict__ pts) {
  int rank = blockIdx.x * TPB + threadIdx.x;
  if (rank >= K_TOP) return;
  int M = meta[0];
  if (rank >= M) {
    boxes[rank] = make_float4(0.f, 0.f, 0.f, 0.f);
    cs[rank] = make_float2(0.f, 0.f);
    #pragma unroll
    for (int k = 0; k < 10; ++k) pts[rank*10 + k] = 0.f;
    return;
  }
  int n = sel[rank];
  int pi = n % P;
  float sx = scalar_to_float(psx), sy = scalar_to_float(psy);
  float4 pr = ((const float4*)priors)[pi];
  float4 lo = ((const float4*)loc)[n];
  // ctr = p[:2] + (loc[:2]*VAR0)*p[2:]
  float cx = __fadd_rn(pr.x, __fmul_rn(__fmul_rn(lo.x, 0.1f), pr.z));
  float cy = __fadd_rn(pr.y, __fmul_rn(__fmul_rn(lo.y, 0.1f), pr.w));
  // wh = p[2:] * exp(loc[2:]*VAR1)
  float w  = __fmul_rn(pr.z, expf(__fmul_rn(lo.z, 0.2f)));
  float h  = __fmul_rn(pr.w, expf(__fmul_rn(lo.w, 0.2f)));
  float hw = __fmul_rn(w, 0.5f), hh = __fmul_rn(h, 0.5f);
  float4 b;
  b.x = __fmul_rn(__fsub_rn(cx, hw), sx);
  b.y = __fmul_rn(__fsub_rn(cy, hh), sy);
  b.z = __fmul_rn(__fadd_rn(cx, hw), sx);
  b.w = __fmul_rn(__fadd_rn(cy, hh), sy);
  boxes[rank] = b;
  cs[rank] = ((const float2*)conf)[n];
  const float2* l2 = (const float2*)landms;
  #pragma unroll
  for (int k = 0; k < 5; ++k) {
    float2 lm = l2[(long long)n*5 + k];
    // pts = (p[:2] + ((p[2:]*l)*VAR0)) * scale
    float px = __fmul_rn(__fadd_rn(pr.x, __fmul_rn(__fmul_rn(pr.z, lm.x), 0.1f)), sx);
    float py = __fmul_rn(__fadd_rn(pr.y, __fmul_rn(__fmul_rn(pr.w, lm.y), 0.1f)), sy);
    pts[rank*10 + 2*k]     = px;
    pts[rank*10 + 2*k + 1] = py;
  }
}

// ---------------- pass 5: suppression bit-matrix ----------------
__device__ __forceinline__ float box_area(float4 a) {
  return __fmul_rn(fmaxf(__fsub_rn(a.z, a.x), 0.f), fmaxf(__fsub_rn(a.w, a.y), 0.f));
}

__global__ __launch_bounds__(64)
void iou_kernel(const float4* __restrict__ boxes, u64* __restrict__ mat) {
  int cb = blockIdx.x;            // col word 0..79
  int rb = blockIdx.y;            // row block 0..78
  int t  = threadIdx.x;
  __shared__ float4 cbox[64];
  __shared__ float  carea[64];
  int j0 = cb * 64;
  int jj = j0 + t;
  float4 bj = (jj < K_TOP) ? boxes[jj] : make_float4(0.f, 0.f, 0.f, 0.f);
  cbox[t]  = bj;
  carea[t] = box_area(bj);
  __syncthreads();
  int i = rb * 64 + t;
  if (i >= K_TOP) return;
  size_t widx = (size_t)i * W_WORDS + cb;
  if (j0 + 63 <= i) { mat[widx] = 0ull; return; }   // whole word is j<=i
  float4 bi = boxes[i];
  float ai = box_area(bi);
  u64 bits = 0;
  #pragma unroll 8
  for (int q = 0; q < 64; ++q) {
    float4 b = cbox[q];
    float iw = fmaxf(__fsub_rn(fminf(bi.z, b.z), fmaxf(bi.x, b.x)), 0.f);
    float ih = fmaxf(__fsub_rn(fminf(bi.w, b.w), fmaxf(bi.y, b.y)), 0.f);
    float inter = __fmul_rn(iw, ih);
    float uni = __fsub_rn(__fadd_rn(ai, carea[q]), inter);
    float iou = __fdiv_rn(inter, fmaxf(uni, 1e-12f));
    int j = j0 + q;
    bits |= (u64)((iou > NMS_THR_F) & (j > i)) << q;
  }
  mat[widx] = bits;
}

// ---------------- pass 6: serial greedy reduce, LDS-pipelined -----------------
// Single wave. Tiles of TR=16 rows stream global->LDS via global_load_lds
// (zero VGPR staging), 6 slots / depth-5 (50 outstanding <= vmcnt max 63).
// Per tile: batched ds_reads, unconditional readlane prefetch of the 16
// diagonal words, branchless SALU keep-chain, uniform-branch apply.
#define TR 16
#define PIPE 6
#define TILE_WORDS (TR * W_WORDS)            // 1280 u64
#define TILE_BYTES (TILE_WORDS * 8)          // 10240 B
#define COPIES_PER_TILE (TILE_BYTES / 1024)  // 10 (64 lanes x 16 B each)

__device__ __forceinline__ u64 readlane_u64(u64 v, int lane) {
  unsigned lo = (unsigned)__builtin_amdgcn_readlane((int)(unsigned)(v & 0xffffffffull), lane);
  unsigned hi = (unsigned)__builtin_amdgcn_readlane((int)(unsigned)(v >> 32), lane);
  return ((u64)hi << 32) | lo;
}

__device__ __forceinline__ void async_copy16(const void* g, void* l) {
  __builtin_amdgcn_global_load_lds((const __attribute__((address_space(1))) void*)g,
                                   (__attribute__((address_space(3))) void*)l,
                                   16, 0, 0);
}

__device__ __forceinline__ void issue_tile(const char* matb, u64* slotp, int tile, int lane) {
  const char* src = matb + (size_t)tile * TILE_BYTES + (size_t)lane * 16;
  char* dst = (char*)slotp;                  // wave-uniform; HW adds lane*16
  #pragma unroll
  for (int c = 0; c < COPIES_PER_TILE; ++c)
    async_copy16(src + c * 1024, dst + c * 1024);
}

__global__ __launch_bounds__(64)
void nms_reduce_kernel(const u64* __restrict__ mat, const int* __restrict__ meta,
                       u64* __restrict__ keepw) {
  __shared__ __align__(16) u64 sbuf[PIPE][TILE_WORDS];   // 60 KB
  int t = threadIdx.x;
  int M = meta[0];
  // drain the meta load so it can't pollute counted vmcnt arithmetic below
  asm volatile("s_waitcnt vmcnt(0) lgkmcnt(0)" ::: "memory");
  __builtin_amdgcn_sched_barrier(0);

  const char* matb = (const char*)mat;
  const int NT = (K_TOP + TR - 1) / TR;      // 313
  // deep prefetch: tiles 0..4
  issue_tile(matb, sbuf[0], 0, t);
  issue_tile(matb, sbuf[1], 1, t);
  issue_tile(matb, sbuf[2], 2, t);
  issue_tile(matb, sbuf[3], 3, t);
  issue_tile(matb, sbuf[4], 4, t);

  auto initw = [&](int w) -> u64 {
    int start = w * 64;
    if (M <= start) return ~0ull;            // fully invalid -> removed
    if (M >= start + 64) return 0ull;        // fully valid
    return (~0ull) << (M - start);           // bits >= M removed
  };
  u64 r0w = initw(t);                        // removed-state word t
  u64 r1w = (t < 16) ? initw(64 + t) : ~0ull; // lanes 0..15 own words 64..79

  int slot_i = 0;                            // g % PIPE
  int slot_p = 5 % PIPE;                     // (g+5) % PIPE
  for (int g = 0; g < NT; ++g) {
    if (g + 5 < NT) {
      issue_tile(matb, sbuf[slot_p], g + 5, t);
      asm volatile("s_waitcnt vmcnt(50)" ::: "memory");
    } else {
      int rem = NT - 1 - g;
      if      (rem == 4) { asm volatile("s_waitcnt vmcnt(40)" ::: "memory"); }
      else if (rem == 3) { asm volatile("s_waitcnt vmcnt(30)" ::: "memory"); }
      else if (rem == 2) { asm volatile("s_waitcnt vmcnt(20)" ::: "memory"); }
      else if (rem == 1) { asm volatile("s_waitcnt vmcnt(10)" ::: "memory"); }
      else               { asm volatile("s_waitcnt vmcnt(0)"  ::: "memory"); }
    }
    __builtin_amdgcn_sched_barrier(0);

    const u64* slot = sbuf[slot_i];
    u64 w0[TR], w1[TR];
    #pragma unroll
    for (int r = 0; r < TR; ++r) {           // batch all ds_reads up front
      w0[r] = slot[r * W_WORDS + t];
      w1[r] = slot[r * W_WORDS + 64 + (t & 15)];
    }
    // ---- prefetch the 16 diagonal words (independent readlanes, no branches) --
    int i0 = g * TR;
    int wi = i0 >> 6;                        // uniform 0..78 (16 | 64)
    int sh = i0 & 63;                        // 0,16,32,48
    u64 cur, d[TR];
    if (wi < 64) {                           // uniform branch, taken for g < 256
      cur = readlane_u64(r0w, wi);
      #pragma unroll
      for (int r = 0; r < TR; ++r) d[r] = readlane_u64(w0[r], wi);
    } else {
      cur = readlane_u64(r1w, wi - 64);
      #pragma unroll
      for (int r = 0; r < TR; ++r) d[r] = readlane_u64(w1[r], wi - 64);
    }
    // ---- branchless SALU keep-chain ----
    unsigned keep16 = 0;
    #pragma unroll
    for (int r = 0; r < TR; ++r) {
      u64 removed = (cur >> (sh + r)) & 1ull;
      u64 live = (i0 + r < K_TOP) ? (removed ^ 1ull) : 0ull;
      cur |= d[r] & (0ull - live);           // in-tile forward suppression
      keep16 |= (unsigned)live << r;
    }
    // ---- apply kept rows' full-width masks (uniform branches) ----
    #pragma unroll
    for (int r = 0; r < TR; ++r) {
      if ((keep16 >> r) & 1u) {
        r0w |= w0[r];
        r1w |= w1[r];                        // lanes t>=16 compute garbage, never stored
      }
    }
    slot_i = (slot_i + 1) % PIPE;
    slot_p = (slot_p + 1) % PIPE;
  }
  keepw[t] = ~r0w;
  if (t < 16) keepw[64 + t] = ~r1w;
}

// ---------------- pass 7: final masked write ----------------
__global__ __launch_bounds__(TPB)
void finalize_kernel(const float4* __restrict__ boxes, const float2* __restrict__ cs,
                     const float* __restrict__ pts, const u64* __restrict__ keepw,
                     float* __restrict__ out) {
  int rank = blockIdx.x * TPB + threadIdx.x;
  if (rank >= K_TOP) return;
  float m = ((keepw[rank >> 6] >> (rank & 63)) & 1ull) ? 1.0f : 0.0f;
  const int PTS_OFF  = K_TOP * 2;    // 10000
  const int BOX_OFF  = K_TOP * 12;   // 60000
  const int KEEP_OFF = K_TOP * 16;   // 80000
  float2 c = cs[rank];
  out[rank*2 + 0] = c.x * m;
  out[rank*2 + 1] = c.y * m;
  #pragma unroll
  for (int k = 0; k < 10; ++k) out[PTS_OFF + rank*10 + k] = pts[rank*10 + k] * m;
  float4 b = boxes[rank];
  out[BOX_OFF + rank*4 + 0] = b.x * m;
  out[BOX_OFF + rank*4 + 1] = b.y * m;
  out[BOX_OFF + rank*4 + 2] = b.z * m;
  out[BOX_OFF + rank*4 + 3] = b.w * m;
  out[KEEP_OFF + rank] = m;
}

extern "C" void kernel_launch(void* const* d_in, const int* in_sizes, int n_in,
                              void* d_out, int out_size, void* d_ws, size_t ws_size,
                              hipStream_t stream) {
  const float* loc    = (const float*)d_in[0];
  const float* conf   = (const float*)d_in[1];
  const float* landms = (const float*)d_in[2];
  const float* priors = (const float*)d_in[3];
  const int*   psx    = (const int*)d_in[4];
  const int*   psy    = (const int*)d_in[5];
  int P = in_sizes[3] / 4;
  int N = in_sizes[1] / 2;
  int NB = (N + CHUNK - 1) / CHUNK;

  char* ws = (char*)d_ws;
  size_t off = 0;
  u64*    mat    = (u64*)(ws + off);    off += (size_t)ROWS_PAD * W_WORDS * 8; // 3.24 MB
  u64*    keepw  = (u64*)(ws + off);    off += (size_t)W_WORDS * 8;
  float4* boxes  = (float4*)(ws + off); off += (size_t)K_TOP * 16;
  float2* cs     = (float2*)(ws + off); off += (size_t)K_TOP * 8;
  float*  pts    = (float*)(ws + off);  off += (size_t)K_TOP * 40;
  int*    sel    = (int*)(ws + off);    off += (size_t)K_TOP * 4;
  int*    counts = (int*)(ws + off);    off += (size_t)NB * 4;
  int*    offs   = (int*)(ws + off);    off += (size_t)NB * 4;
  int*    meta   = (int*)(ws + off);    off += 64;

  count_kernel<<<NB, TPB, 0, stream>>>(conf, N, counts);
  scan_kernel<<<1, TPB, 0, stream>>>(counts, offs, meta, NB);
  emit_kernel<<<NB, TPB, 0, stream>>>(conf, N, offs, sel);
  int dgrid = (K_TOP + TPB - 1) / TPB;
  decode_kernel<<<dgrid, TPB, 0, stream>>>(loc, conf, landms, priors, psx, psy,
                                           sel, meta, P, boxes, cs, pts);
  dim3 ig(W_WORDS, (K_TOP + 63) / 64);   // 80 x 79
  iou_kernel<<<ig, 64, 0, stream>>>(boxes, mat);
  nms_reduce_kernel<<<1, 64, 0, stream>>>(mat, meta, keepw);
  finalize_kernel<<<dgrid, TPB, 0, stream>>>(boxes, cs, pts, keepw, (float*)d_out);
}